// Round 7
// baseline (139.562 us; speedup 1.0000x reference)
//
#include <hip/hip_runtime.h>
#include <hip/hip_bf16.h>

#define BB 8
#define TT 2048
#define CC 1024
#define HH 64
#define NSPLIT 8

typedef __attribute__((ext_vector_type(8)))  short bf16x8;
typedef __attribute__((ext_vector_type(4)))  float f32x4;
typedef __attribute__((ext_vector_type(16))) float f32x16;
typedef __attribute__((ext_vector_type(8)))  unsigned short us8;
typedef unsigned int u32;

static __device__ __forceinline__ unsigned short f2bf(float f) {
    union { float f; unsigned int u; } v; v.f = f;
    unsigned int u = v.u;
    return (unsigned short)((u + 0x7FFFu + ((u >> 16) & 1u)) >> 16);  // RNE
}
static __device__ __forceinline__ float bf2f(unsigned short s) {
    union { u32 u; float f; } v; v.u = ((u32)s) << 16; return v.f;
}

// ---------------------------------------------------------------------------
// Kernel 0: W [C][H] fp32 -> Wt [3][H][C] bf16 (transposed), fold log2(e)/8
// into Wq so QK^T scores come out in the log2 domain.
// ---------------------------------------------------------------------------
__global__ __launch_bounds__(256) void prep_weights(
        const float* __restrict__ Wq, const float* __restrict__ Wk,
        const float* __restrict__ Wv, unsigned short* __restrict__ Wt) {
    __shared__ float tile[64][65];
    int w  = blockIdx.x >> 4;       // 0..2
    int c0 = (blockIdx.x & 15) * 64;
    const float* W = (w == 0) ? Wq : (w == 1) ? Wk : Wv;
    int li = threadIdx.x;
    {
        int c = li >> 2, h4 = (li & 3) * 16;
        const float* src = W + (size_t)(c0 + c) * HH + h4;
        #pragma unroll
        for (int i = 0; i < 4; ++i) {
            float4 v4 = *(const float4*)(src + i * 4);
            tile[c][h4 + i*4 + 0] = v4.x; tile[c][h4 + i*4 + 1] = v4.y;
            tile[c][h4 + i*4 + 2] = v4.z; tile[c][h4 + i*4 + 3] = v4.w;
        }
    }
    __syncthreads();
    float scale = (w == 0) ? 0.1803368802f : 1.0f;   // log2(e)/sqrt(64)
    int h = li >> 2, cg = (li & 3) * 16;
    unsigned short* dst = Wt + (size_t)w * HH * CC + (size_t)h * CC + c0 + cg;
    #pragma unroll
    for (int i = 0; i < 16; ++i) dst[i] = f2bf(tile[cg + i][h] * scale);
}

// ---------------------------------------------------------------------------
// Kernel 1: fused QKV projection — round-4 PASSED version, verbatim.
// ---------------------------------------------------------------------------
__global__ __launch_bounds__(512, 4) void proj_qkv(
        const float* __restrict__ x, const unsigned short* __restrict__ Wt,
        unsigned short* __restrict__ qws, unsigned short* __restrict__ kws,
        unsigned short* __restrict__ vws) {
    __shared__ unsigned short Xs[2][32 * 64];    // 4 KB each
    __shared__ unsigned short Ws[2][192 * 64];   // 24 KB each
    int tid = threadIdx.x;
    int wv = tid >> 6, lane = tid & 63;
    int quad = (lane >> 4) & 3, lq = lane & 15;
    int mg = wv >> 2, ng = wv & 3;
    int r0 = blockIdx.x * 32;

    bool xact = tid < 256;
    int xr = tid >> 3, xg = tid & 7;
    const float* xsrc = x + (size_t)(r0 + xr) * CC + xg * 8;
    int xdst = xr * 64 + ((xg ^ (xr & 7)) * 8);
    float4 xa[2], xb[2];                         // 2-deep prefetch sets

    f32x4 acc[3];
    #pragma unroll
    for (int nt = 0; nt < 3; ++nt)
        #pragma unroll
        for (int i = 0; i < 4; ++i) acc[nt][i] = 0.0f;

    auto stageW = [&](int buf, int kc) {
        #pragma unroll
        for (int i = 0; i < 3; ++i) {
            int fp = tid + i * 512;            // 0..1535
            int r = fp >> 3, pb = fp & 7, g = pb ^ (r & 7);
            const u32 __attribute__((address_space(1)))* gsrc =
                (const u32 __attribute__((address_space(1)))*)
                    (Wt + (size_t)r * CC + kc * 64 + g * 8);
            u32 __attribute__((address_space(3)))* ldst =
                (u32 __attribute__((address_space(3)))*)(&Ws[buf][fp * 8]);
            __builtin_amdgcn_global_load_lds(gsrc, ldst, 16, 0, 0);
        }
    };
    auto loadX = [&](int set, int kc) {
        xa[set] = *(const float4*)(xsrc + kc * 64);
        xb[set] = *(const float4*)(xsrc + kc * 64 + 4);
    };
    auto writeX = [&](int set, int buf) {
        unsigned short h[8];
        h[0]=f2bf(xa[set].x); h[1]=f2bf(xa[set].y);
        h[2]=f2bf(xa[set].z); h[3]=f2bf(xa[set].w);
        h[4]=f2bf(xb[set].x); h[5]=f2bf(xb[set].y);
        h[6]=f2bf(xb[set].z); h[7]=f2bf(xb[set].w);
        *(us8*)&Xs[buf][xdst] = *(const us8*)h;
    };

    // prologue: X[0] -> buf0 now; X[1] held in regs for iter 0's stage phase
    if (xact) { loadX(0, 0); loadX(1, 1); }
    stageW(0, 0);
    if (xact) writeX(0, 0);

    for (int kc = 0; kc < 16; ++kc) {
        int cur = kc & 1;
        __syncthreads();                     // buf[cur] ready; buf[1-cur] free
        if (kc < 15) stageW(1 - cur, kc + 1);
        if (xact && kc < 14) loadX(kc & 1, kc + 2);   // refill freed set
        #pragma unroll
        for (int ks = 0; ks < 2; ++ks) {
            int g = ks * 4 + quad;
            int arow = mg * 16 + lq;
            bf16x8 a = *(const bf16x8*)&Xs[cur][arow * 64 + (g ^ (lq & 7)) * 8];
            bf16x8 b[3];
            #pragma unroll
            for (int nt = 0; nt < 3; ++nt) {
                int brow = ng * 48 + nt * 16 + lq;
                b[nt] = *(const bf16x8*)&Ws[cur][brow * 64 + (g ^ (lq & 7)) * 8];
            }
            #pragma unroll
            for (int nt = 0; nt < 3; ++nt)
                acc[nt] = __builtin_amdgcn_mfma_f32_16x16x32_bf16(
                    a, b[nt], acc[nt], 0, 0, 0);
        }
        if (xact && kc < 15) writeX((kc + 1) & 1, 1 - cur);  // X[kc+1]
    }

    // epilogue: q,k direct; v via LDS transpose then coalesced us8 stores.
    __syncthreads();
    unsigned short* Vl = (unsigned short*)Xs;   // [h][row], pitch 36
    #pragma unroll
    for (int nt = 0; nt < 3; ++nt) {
        int g = ng * 48 + nt * 16 + lq;
        #pragma unroll
        for (int i = 0; i < 4; ++i) {
            int row = mg * 16 + quad * 4 + i;
            unsigned short bv = f2bf(acc[nt][i]);
            if (g < 64)       qws[(size_t)(r0 + row) * HH + g] = bv;
            else if (g < 128) kws[(size_t)(r0 + row) * HH + (g - 64)] = bv;
            else              Vl[(g - 128) * 36 + row] = bv;
        }
    }
    __syncthreads();
    if (tid < 256) {
        int h = tid >> 2, tb = (tid & 3) * 8;
        int b = r0 >> 11, rr = r0 & (TT - 1);
        *(us8*)(vws + ((size_t)b * HH + h) * TT + rr + tb) =
            *(const us8*)&Vl[h * 36 + tb];
    }
}

// ---------------------------------------------------------------------------
// Kernel 2: causal attention — round-4 structure + KV-split 8 with bf16
// partials (same partial HBM bytes as round-4's fp32 x4 splits).
// ---------------------------------------------------------------------------
__global__ __launch_bounds__(128, 3) void attn(
        const unsigned short* __restrict__ qws,
        const unsigned short* __restrict__ kws,
        const unsigned short* __restrict__ vws,
        unsigned short* __restrict__ Op, float* __restrict__ Lp) {
    __shared__ unsigned short Kt[32][72];   // [key][h]
    __shared__ unsigned short Vt[64][40];   // [h][key]
    __shared__ unsigned short Ps[64][40];   // [q][key], rows wave-private
    int ti = blockIdx.x;            // 64-row q tile, 0..31
    int s  = blockIdx.y;            // kv split 0..NSPLIT-1
    int b  = blockIdx.z;
    int last = 2 * ti + 1;          // last 32-key chunk index for this tile
    if (s > last) return;
    int tid = threadIdx.x, wv = tid >> 6, lane = tid & 63;
    int half = lane >> 5, l31 = lane & 31;

    bf16x8 qf[4];
    {
        const unsigned short* qp =
            qws + ((size_t)b * TT + ti * 64 + wv * 32 + l31) * HH + half * 8;
        #pragma unroll
        for (int ks = 0; ks < 4; ++ks) qf[ks] = *(const bf16x8*)(qp + ks * 16);
    }
    f32x16 O0, O1, Lc;
    #pragma unroll
    for (int i = 0; i < 16; ++i) { O0[i] = 0.f; O1[i] = 0.f; Lc[i] = 0.f; }
    bf16x8 ones;
    #pragma unroll
    for (int i = 0; i < 8; ++i) ones[i] = (short)0x3F80;

    for (int jc = s; jc <= last; jc += NSPLIT) {
        __syncthreads();   // prior iter's K/V reads done before restage
        #pragma unroll
        for (int i = 0; i < 2; ++i) {   // K: 32 keys x 64 h
            int slot = tid + i * 128;
            int r = slot >> 3, g = slot & 7;
            *(us8*)&Kt[r][g * 8] =
                *(const us8*)(kws + ((size_t)b * TT + jc * 32 + r) * HH + g * 8);
        }
        #pragma unroll
        for (int i = 0; i < 2; ++i) {   // V: 64 h x 32 keys
            int slot = tid + i * 128;
            int h = slot >> 2, kb = slot & 3;
            *(us8*)&Vt[h][kb * 8] =
                *(const us8*)(vws + ((size_t)b * HH + h) * TT + jc * 32 + kb * 8);
        }
        __syncthreads();
        f32x16 S;
        #pragma unroll
        for (int i = 0; i < 16; ++i) S[i] = 0.f;
        #pragma unroll
        for (int ks = 0; ks < 4; ++ks) {
            bf16x8 kf = *(const bf16x8*)&Kt[l31][ks * 16 + half * 8];
            S = __builtin_amdgcn_mfma_f32_32x32x16_bf16(qf[ks], kf, S, 0, 0, 0);
        }
        bool diag = (jc >= 2 * ti + wv);   // chunk can touch this wave's diagonal
        #pragma unroll
        for (int r = 0; r < 16; ++r) {
            int pat = (r & 3) + 8 * (r >> 2) + 4 * half;    // local q row in wave
            float p = __builtin_amdgcn_exp2f(S[r]);
            if (diag && jc * 32 + l31 > ti * 64 + wv * 32 + pat) p = 0.0f;
            Ps[wv * 32 + pat][l31] = f2bf(p);
        }
        // no __syncthreads: each wave reads only its own 32 Ps rows
        #pragma unroll
        for (int ks = 0; ks < 2; ++ks) {
            bf16x8 pa  = *(const bf16x8*)&Ps[wv * 32 + l31][ks * 16 + half * 8];
            bf16x8 vf0 = *(const bf16x8*)&Vt[l31][ks * 16 + half * 8];
            bf16x8 vf1 = *(const bf16x8*)&Vt[32 + l31][ks * 16 + half * 8];
            O0 = __builtin_amdgcn_mfma_f32_32x32x16_bf16(pa, vf0, O0, 0, 0, 0);
            O1 = __builtin_amdgcn_mfma_f32_32x32x16_bf16(pa, vf1, O1, 0, 0, 0);
            Lc = __builtin_amdgcn_mfma_f32_32x32x16_bf16(pa, ones, Lc, 0, 0, 0);
        }
    }
    // deterministic per-split partial store (bf16)
    unsigned short* Ob =
        Op + (((size_t)s * BB + b) * TT + ti * 64 + wv * 32) * HH;
    #pragma unroll
    for (int r = 0; r < 16; ++r) {
        int pat = (r & 3) + 8 * (r >> 2) + 4 * half;
        Ob[(size_t)pat * HH + l31]      = f2bf(O0[r]);
        Ob[(size_t)pat * HH + 32 + l31] = f2bf(O1[r]);
    }
    if (l31 == 0) {
        #pragma unroll
        for (int r = 0; r < 16; ++r) {
            int pat = (r & 3) + 8 * (r >> 2) + 4 * half;
            Lp[((size_t)s * BB + b) * TT + ti * 64 + wv * 32 + pat] = Lc[r];
        }
    }
}

// ---------------------------------------------------------------------------
// Kernel 3: out = (sum_s Op[s]) / (sum_s Lp[s]). 4 threads/row x 16384 rows
// = 65536 threads = 256 blocks. ROUND-5/6 CRASH FIX: grid was 2048 blocks
// (8x too many) -> g ran to 131071 vs 16384 valid rows -> stores up to 32 MB
// past d_out -> abort. Only ns=min(2ti+2,NSPLIT) splits exist per q-tile.
// ---------------------------------------------------------------------------
__global__ __launch_bounds__(256) void norm_out(
        const unsigned short* __restrict__ Op, const float* __restrict__ Lp,
        float* __restrict__ out) {
    int idx = blockIdx.x * 256 + threadIdx.x;     // 65536 total
    int g = idx >> 2;                             // global row b*T + t, <16384
    int hseg = (idx & 3) * 16;
    int ti = (g & (TT - 1)) >> 6;
    int ns = min(2 * ti + 2, NSPLIT);
    float a[16];
    #pragma unroll
    for (int j = 0; j < 16; ++j) a[j] = 0.f;
    float Ls = 0.f;
    for (int s = 0; s < ns; ++s) {
        const unsigned short* base =
            Op + ((size_t)s * BB * TT + g) * HH + hseg;
        us8 u0 = *(const us8*)base;
        us8 u1 = *(const us8*)(base + 8);
        #pragma unroll
        for (int j = 0; j < 8; ++j) { a[j] += bf2f(u0[j]); a[8 + j] += bf2f(u1[j]); }
        Ls += Lp[(size_t)s * BB * TT + g];
    }
    float inv = 1.0f / Ls;
    float* ob = out + (size_t)g * HH + hseg;
    #pragma unroll
    for (int q = 0; q < 4; ++q) {
        float4 v = make_float4(a[q*4] * inv, a[q*4+1] * inv,
                               a[q*4+2] * inv, a[q*4+3] * inv);
        ((float4*)ob)[q] = v;
    }
}

// ---------------------------------------------------------------------------
extern "C" void kernel_launch(void* const* d_in, const int* in_sizes, int n_in,
                              void* d_out, int out_size, void* d_ws, size_t ws_size,
                              hipStream_t stream) {
    (void)in_sizes; (void)n_in; (void)out_size; (void)ws_size;
    const float* x  = (const float*)d_in[0];
    const float* Wq = (const float*)d_in[1];
    const float* Wk = (const float*)d_in[2];
    const float* Wv = (const float*)d_in[3];
    float* out = (float*)d_out;

    char* ws = (char*)d_ws;
    unsigned short* Wt  = (unsigned short*)ws;                          // 384 KB
    unsigned short* qws = (unsigned short*)(ws + (1u << 19));           // 2 MB
    unsigned short* kws = (unsigned short*)(ws + (1u << 19) + (1u << 21));
    unsigned short* vws = (unsigned short*)(ws + (1u << 19) + (2u << 21));
    unsigned short* Op  = (unsigned short*)(ws + (1u << 19) + (3u << 21)); // 16 MB bf16
    float*          Lp  = (float*)(ws + (1u << 19) + (3u << 21) + (1u << 24)); // 512 KB

    prep_weights<<<48, 256, 0, stream>>>(Wq, Wk, Wv, Wt);
    proj_qkv<<<512, 512, 0, stream>>>(x, Wt, qws, kws, vws);
    attn<<<dim3(32, NSPLIT, 8), 128, 0, stream>>>(qws, kws, vws, Op, Lp);
    norm_out<<<256, 256, 0, stream>>>(Op, Lp, out);
}